// Round 2
// baseline (180.206 us; speedup 1.0000x reference)
//
#include <hip/hip_runtime.h>

#define BATCH   1024
#define GROUPS  512

typedef float f32x4 __attribute__((ext_vector_type(4)));

// No LDS at all. params = 512*16*64*4B = 2 MB total -> fits (replicated) in
// every XCD's 4 MiB L2, so the per-row gathers are L2 reads (~512 MB @ 34.5
// TB/s aggregate = ~15 us, overlapped with the write stream). The previous
// LDS-staging design paid 64 MB of HBM re-reads + a barrier for data that was
// already cache-resident (Common-mistake #7).
//
// Block = 1 batch x 256 groups (half the group dim). Wave w sweeps its 64
// consecutive groups in ascending order: 16 iterations x 1 KiB contiguous
// stores = ONE strictly-ascending 16 KiB stream per wave -- the same
// many-sequential-streams write pattern the 6.3 TB/s fill kernel uses.
// Lane map: gl=(tid>>4)&3 (group within iteration), c4=tid&15 (float4 column).
// Stores are nontemporal so the 134 MB output stream does not evict the 2 MB
// param set from L2.
__global__ __launch_bounds__(256) void hoact_kernel(
    const float4* __restrict__ X4,   // [B*G]       (4 f32 -> one float4)
    const float4* __restrict__ P4,   // [G*256]     (16 rows x 16 float4)
    float4*       __restrict__ O4)   // [B*G*16]
{
    const int tid = threadIdx.x;
    const int b   = blockIdx.x >> 1;        // 0..1023
    const int h   = blockIdx.x & 1;         // group half: 0 or 1
    const int w   = tid >> 6;               // wave 0..3
    const int gl  = (tid >> 4) & 3;         // group within one iteration
    const int c4  = tid & 15;               // float4 column within D=64

    const int  gw0  = h * 256 + w * 64;     // wave's 64-group span
    const long xoff = (long)b * GROUPS;
    const long ooff = (long)b * (GROUPS * 16);

#pragma unroll
    for (int half = 0; half < 2; ++half) {
        // prefetch 8 iterations of X (16-lane broadcast, 64B/wave contiguous)
        float4 xv[8];
#pragma unroll
        for (int j = 0; j < 8; ++j) {
            const int g = gw0 + (half * 8 + j) * 4 + gl;
            xv[j] = X4[xoff + g];
        }

#pragma unroll
        for (int j = 0; j < 8; ++j) {
            const int g = gw0 + (half * 8 + j) * 4 + gl;
            const float4 x = xv[j];

            // pack 2-bit source index into mantissa LSBs (<=3 ULP, harmless);
            // sort via fmin/fmax network; ties -> zero gap coef (stable order
            // preserved since equal values keep index order via LSBs).
            float v0 = __uint_as_float((__float_as_uint(x.x) & ~3u) | 0u);
            float v1 = __uint_as_float((__float_as_uint(x.y) & ~3u) | 1u);
            float v2 = __uint_as_float((__float_as_uint(x.z) & ~3u) | 2u);
            float v3 = __uint_as_float((__float_as_uint(x.w) & ~3u) | 3u);

#define CSWAP(a, b_)                                 \
            {                                        \
                const float lo = fminf((a), (b_));   \
                const float hi = fmaxf((a), (b_));   \
                (a) = lo; (b_) = hi;                 \
            }
            CSWAP(v0, v1);
            CSWAP(v2, v3);
            CSWAP(v0, v2);
            CSWAP(v1, v3);
            CSWAP(v1, v2);
#undef CSWAP

            const int i1 = __float_as_uint(v1) & 3;
            const int i2 = __float_as_uint(v2) & 3;
            const int i3 = __float_as_uint(v3) & 3;

            const float c0 = v0;
            const float c1 = v1 - v0;
            const float c2 = v2 - v1;
            const float c3 = v3 - v2;

            const int e3 = 1 << i3;
            const int e2 = e3 + (1 << i2);
            const int e1 = e2 + (1 << i1);
            // e0 == 15 always

            // gathers: 16-lane group reads 4 x 256B contiguous row slices
            // from L2-resident params
            const int  gbase = g << 8;               // g * 256 float4s
            const f32x4 p0 = *(const f32x4*)&P4[gbase + (15 << 4) + c4];
            const f32x4 p1 = *(const f32x4*)&P4[gbase + (e1 << 4) + c4];
            const f32x4 p2 = *(const f32x4*)&P4[gbase + (e2 << 4) + c4];
            const f32x4 p3 = *(const f32x4*)&P4[gbase + (e3 << 4) + c4];

            f32x4 o;
            o.x = c0 * p0.x + c1 * p1.x + c2 * p2.x + c3 * p3.x;
            o.y = c0 * p0.y + c1 * p1.y + c2 * p2.y + c3 * p3.y;
            o.z = c0 * p0.z + c1 * p1.z + c2 * p2.z + c3 * p3.z;
            o.w = c0 * p0.w + c1 * p1.w + c2 * p2.w + c3 * p3.w;

            // wave's 64 lanes: 1 KiB contiguous, strictly ascending across j
            __builtin_nontemporal_store(o, (f32x4*)&O4[ooff + (g << 4) + c4]);
        }
    }
}

extern "C" void kernel_launch(void* const* d_in, const int* in_sizes, int n_in,
                              void* d_out, int out_size, void* d_ws, size_t ws_size,
                              hipStream_t stream) {
    const float4* X4 = (const float4*)d_in[0];   // X: [1024, 512, 4] fp32
    const float4* P4 = (const float4*)d_in[1];   // params: [512, 16, 64] fp32
    float4*       O4 = (float4*)d_out;           // out: [1024, 512, 64] fp32

    const int grid = BATCH * 2;                  // 2048 blocks, no LDS, no barrier
    hipLaunchKernelGGL(hoact_kernel, dim3(grid), dim3(256), 0, stream,
                       X4, P4, O4);
}

// Round 5
// 144.346 us; speedup vs baseline: 1.2484x; 1.2484x over previous
//
#include <hip/hip_runtime.h>

#define BATCH   1024
#define GROUPS  512
#define OUT_DIM 64

// Row stride in LDS words: 64 data + 4 pad (272 B/row): keeps 16 B alignment
// for ds_read_b128 and shifts each row's bank phase by 4 so the 8 bg-groups
// of a wave (reading data-dependent rows) rarely pile onto the same banks.
#define ROW_WORDS 68

typedef float f32x4 __attribute__((ext_vector_type(4)));

// Structure of the 146us kernel (1 group x b-chunk per block, 8 lanes per
// (b,g), LDS-staged params, plain stores) with three targeted deltas:
//
// 1) XCD-partitioned dispatch: xcd = blockIdx&7 owns groups [64*xcd, 64*xcd+64)
//    and all 4 b-chunks of each group are co-resident on that XCD. Params for
//    a group are fetched from HBM once and L2-hit by the other 3 chunks
//    (param HBM 17 MB -> ~2 MB); the 4 groups sharing each 64B X-line are on
//    the same XCD (X HBM 33 MB -> ~8 MB).
// 2) 256 batches per block (2048 blocks = 8/CU, one fully-resident round;
//    halves the number of staging passes).
// 3) Row 15 of the table (e0 == 15 always) is pass-invariant: hoist its two
//    ds_read_b128 out of the pass loop (-25% LDS read traffic).
//
// r4 compile fix: output accumulators are HIP float4 (ext_vector f32x4 has no
// operator= into HIP_vector_type). LDS reads remain f32x4.
__global__ __launch_bounds__(256) void hoact_kernel(
    const float4* __restrict__ X4,   // [B*G]       (4 f32 -> one float4)
    const float4* __restrict__ P4,   // [G*256]     (16 rows x 16 float4)
    float4*       __restrict__ O4)   // [B*G*16]
{
    __shared__ float tbl[16 * ROW_WORDS];

    const int xcd   = blockIdx.x & 7;
    const int idx   = blockIdx.x >> 3;       // 0..255
    const int g     = xcd * 64 + (idx & 63); // contiguous 64-group slice per XCD
    const int chunk = idx >> 6;              // 0..3
    const int b0    = chunk * 256;
    const int tid   = threadIdx.x;           // 0..255

    // ---- stage params[g] into LDS (row-padded); 4 co-resident chunks of the
    //      same g make this an L2 hit for 3 of the 4 ----
    {
        const float4 v = P4[g * 256 + tid];          // coalesced 4 KiB
        const int row = tid >> 4, c4 = tid & 15;
        *(float4*)&tbl[row * ROW_WORDS + c4 * 4] = v;  // ds_write_b128
    }

    const int t       = tid & 7;             // float4 column within D=64
    const int bl_base = tid >> 3;            // 0..31

    // ---- prefetch X for all 8 passes (independent loads, hide staging) ----
    float4 xv[8];
#pragma unroll
    for (int p = 0; p < 8; ++p) {
        const int b = b0 + p * 32 + bl_base;
        xv[p] = X4[b * GROUPS + g];          // 8 lanes broadcast one address
    }

    __syncthreads();

    // ---- pass-invariant row 15 (e0 == 15 for every input) ----
    const f32x4 p0a = *(const f32x4*)&tbl[15 * ROW_WORDS + t * 4];
    const f32x4 p0b = *(const f32x4*)&tbl[15 * ROW_WORDS + (t + 8) * 4];

#pragma unroll
    for (int p = 0; p < 8; ++p) {
        const int b = b0 + p * 32 + bl_base;
        const float4 x = xv[p];

        // pack 2-bit source index into mantissa LSBs (<=3 ULP, harmless);
        // sort via fmin/fmax network; ties -> zero gap coef.
        float v0 = __uint_as_float((__float_as_uint(x.x) & ~3u) | 0u);
        float v1 = __uint_as_float((__float_as_uint(x.y) & ~3u) | 1u);
        float v2 = __uint_as_float((__float_as_uint(x.z) & ~3u) | 2u);
        float v3 = __uint_as_float((__float_as_uint(x.w) & ~3u) | 3u);

#define CSWAP(a, b_)                                 \
        {                                            \
            const float lo = fminf((a), (b_));       \
            const float hi = fmaxf((a), (b_));       \
            (a) = lo; (b_) = hi;                     \
        }
        CSWAP(v0, v1);
        CSWAP(v2, v3);
        CSWAP(v0, v2);
        CSWAP(v1, v3);
        CSWAP(v1, v2);
#undef CSWAP

        const int i1 = __float_as_uint(v1) & 3;
        const int i2 = __float_as_uint(v2) & 3;
        const int i3 = __float_as_uint(v3) & 3;

        const float c0 = v0;
        const float c1 = v1 - v0;
        const float c2 = v2 - v1;
        const float c3 = v3 - v2;

        const int e3 = 1 << i3;
        const int e2 = e3 + (1 << i2);
        const int e1 = e2 + (1 << i1);
        // e0 == 15 always (hoisted above)

        const f32x4 p1a = *(const f32x4*)&tbl[e1 * ROW_WORDS + t * 4];
        const f32x4 p1b = *(const f32x4*)&tbl[e1 * ROW_WORDS + (t + 8) * 4];
        const f32x4 p2a = *(const f32x4*)&tbl[e2 * ROW_WORDS + t * 4];
        const f32x4 p2b = *(const f32x4*)&tbl[e2 * ROW_WORDS + (t + 8) * 4];
        const f32x4 p3a = *(const f32x4*)&tbl[e3 * ROW_WORDS + t * 4];
        const f32x4 p3b = *(const f32x4*)&tbl[e3 * ROW_WORDS + (t + 8) * 4];

        float4 oa, ob;
        oa.x = c0 * p0a.x + c1 * p1a.x + c2 * p2a.x + c3 * p3a.x;
        oa.y = c0 * p0a.y + c1 * p1a.y + c2 * p2a.y + c3 * p3a.y;
        oa.z = c0 * p0a.z + c1 * p1a.z + c2 * p2a.z + c3 * p3a.z;
        oa.w = c0 * p0a.w + c1 * p1a.w + c2 * p2a.w + c3 * p3a.w;
        ob.x = c0 * p0b.x + c1 * p1b.x + c2 * p2b.x + c3 * p3b.x;
        ob.y = c0 * p0b.y + c1 * p1b.y + c2 * p2b.y + c3 * p3b.y;
        ob.z = c0 * p0b.z + c1 * p1b.z + c2 * p2b.z + c3 * p3b.z;
        ob.w = c0 * p0b.w + c1 * p1b.w + c2 * p2b.w + c3 * p3b.w;

        // out[b][g][:]: 8 lanes -> 128 B contiguous runs; plain stores
        // (nontemporal was common to both regressed rounds)
        const int o_idx = b * (GROUPS * 16) + g * 16 + t;
        O4[o_idx]     = oa;
        O4[o_idx + 8] = ob;
    }
}

extern "C" void kernel_launch(void* const* d_in, const int* in_sizes, int n_in,
                              void* d_out, int out_size, void* d_ws, size_t ws_size,
                              hipStream_t stream) {
    const float4* X4 = (const float4*)d_in[0];   // X: [1024, 512, 4] fp32
    const float4* P4 = (const float4*)d_in[1];   // params: [512, 16, 64] fp32
    float4*       O4 = (float4*)d_out;           // out: [1024, 512, 64] fp32

    const int grid = 2048;                       // 8 XCD x 64 g x 4 b-chunks
    hipLaunchKernelGGL(hoact_kernel, dim3(grid), dim3(256), 0, stream,
                       X4, P4, O4);
}